// Round 1
// baseline (1564.179 us; speedup 1.0000x reference)
//
#include <hip/hip_runtime.h>

// QNetGNN: 2-layer GCN, N=100000 nodes, E=3.2M edges, F: 128 -> 16 -> 32.
// Baseline: atomic scatter-add aggregation. Self-loops folded analytically
// (contribution h[i] * dis[i]^2 added in the elementwise passes, no atomics).

#define NNODES 100000
#define FIN    128
#define FHID   16
#define NACT   32

// ---- degree: count in-edges per dst (self loop added later as +1) ----
__global__ void k_deg(const int* __restrict__ dst, int E, float* __restrict__ deg) {
    int i = blockIdx.x * blockDim.x + threadIdx.x;
    if (i < E) atomicAdd(&deg[dst[i]], 1.0f);
}

// ---- dis = rsqrt(deg + 1) ----
__global__ void k_dis(const float* __restrict__ deg, float* __restrict__ dis, int n) {
    int i = blockIdx.x * blockDim.x + threadIdx.x;
    if (i < n) dis[i] = rsqrtf(deg[i] + 1.0f);
}

// ---- h = x @ W1   [N,128]@[128,16] -> [N,16] ----
__global__ void k_xw1(const float* __restrict__ x, const float* __restrict__ W1,
                      float* __restrict__ h, int n) {
    __shared__ float w[FIN * FHID];   // 8 KB
    for (int i = threadIdx.x; i < FIN * FHID; i += blockDim.x) w[i] = W1[i];
    __syncthreads();
    int r = blockIdx.x * blockDim.x + threadIdx.x;
    if (r >= n) return;
    const float4* xr = (const float4*)(x + (long long)r * FIN);
    float acc[FHID];
#pragma unroll
    for (int c = 0; c < FHID; ++c) acc[c] = 0.f;
#pragma unroll 4
    for (int k4 = 0; k4 < FIN / 4; ++k4) {
        float4 xv = xr[k4];
        int k = k4 * 4;
#pragma unroll
        for (int c = 0; c < FHID; ++c) {
            acc[c] += xv.x * w[(k + 0) * FHID + c] + xv.y * w[(k + 1) * FHID + c]
                    + xv.z * w[(k + 2) * FHID + c] + xv.w * w[(k + 3) * FHID + c];
        }
    }
    float4* hr = (float4*)(h + (long long)r * FHID);
    hr[0] = make_float4(acc[0], acc[1], acc[2], acc[3]);
    hr[1] = make_float4(acc[4], acc[5], acc[6], acc[7]);
    hr[2] = make_float4(acc[8], acc[9], acc[10], acc[11]);
    hr[3] = make_float4(acc[12], acc[13], acc[14], acc[15]);
}

// ---- edge aggregation: agg[dst] += feat[src] * dis[src]*dis[dst], 16-wide ----
// 4 threads per edge, each handles a float4 chunk.
__global__ void k_agg(const int* __restrict__ src, const int* __restrict__ dst,
                      const float* __restrict__ dis, const float* __restrict__ feat,
                      float* __restrict__ agg, int E) {
    int t = blockIdx.x * blockDim.x + threadIdx.x;
    int e = t >> 2, p = t & 3;
    if (e >= E) return;
    int s = src[e], d = dst[e];
    float nrm = dis[s] * dis[d];
    float4 v = ((const float4*)(feat + (long long)s * FHID))[p];
    float* o = agg + (long long)d * FHID + p * 4;
    atomicAdd(o + 0, v.x * nrm);
    atomicAdd(o + 1, v.y * nrm);
    atomicAdd(o + 2, v.z * nrm);
    atomicAdd(o + 3, v.w * nrm);
}

// ---- h1 = relu(agg1 + h*dis^2 + b1), written in place over agg1 ----
__global__ void k_relu_bias_self(const float* __restrict__ agg1, const float* __restrict__ h,
                                 const float* __restrict__ dis, const float* __restrict__ b1,
                                 float* __restrict__ h1, int n) {
    int t = blockIdx.x * blockDim.x + threadIdx.x;
    int i = t >> 2, p = t & 3;
    if (i >= n) return;
    float w = dis[i] * dis[i];          // self-loop norm = 1/(deg+1)
    float4 a  = ((const float4*)agg1)[i * 4 + p];
    float4 hv = ((const float4*)h)[i * 4 + p];
    float4 bv = ((const float4*)b1)[p];
    float4 r;
    r.x = fmaxf(a.x + hv.x * w + bv.x, 0.f);
    r.y = fmaxf(a.y + hv.y * w + bv.y, 0.f);
    r.z = fmaxf(a.z + hv.z * w + bv.z, 0.f);
    r.w = fmaxf(a.w + hv.w * w + bv.w, 0.f);
    ((float4*)h1)[i * 4 + p] = r;
}

// ---- out = (agg2 + h1*dis^2) @ W2 + b2   [N,16]@[16,32] -> [N,32] ----
// 8 threads per node, each computes 4 output columns.
__global__ void k_out(const float* __restrict__ agg2, const float* __restrict__ h1,
                      const float* __restrict__ dis, const float* __restrict__ W2,
                      const float* __restrict__ b2, float* __restrict__ out, int n) {
    __shared__ float w[FHID * NACT];   // 2 KB
    __shared__ float bb[NACT];
    for (int i = threadIdx.x; i < FHID * NACT; i += blockDim.x) w[i] = W2[i];
    if (threadIdx.x < NACT) bb[threadIdx.x] = b2[threadIdx.x];
    __syncthreads();
    int t = blockIdx.x * blockDim.x + threadIdx.x;
    int i = t >> 3, p = t & 7;
    if (i >= n) return;
    float invd = dis[i] * dis[i];
    float v[FHID];
    const float4* a4 = (const float4*)(agg2 + (long long)i * FHID);
    const float4* h4 = (const float4*)(h1 + (long long)i * FHID);
#pragma unroll
    for (int q = 0; q < 4; ++q) {
        float4 a = a4[q], hh = h4[q];
        v[q * 4 + 0] = a.x + hh.x * invd;
        v[q * 4 + 1] = a.y + hh.y * invd;
        v[q * 4 + 2] = a.z + hh.z * invd;
        v[q * 4 + 3] = a.w + hh.w * invd;
    }
    float acc0 = bb[p * 4 + 0], acc1 = bb[p * 4 + 1], acc2 = bb[p * 4 + 2], acc3 = bb[p * 4 + 3];
#pragma unroll
    for (int c = 0; c < FHID; ++c) {
        float vc = v[c];
        acc0 += vc * w[c * NACT + p * 4 + 0];
        acc1 += vc * w[c * NACT + p * 4 + 1];
        acc2 += vc * w[c * NACT + p * 4 + 2];
        acc3 += vc * w[c * NACT + p * 4 + 3];
    }
    ((float4*)out)[(long long)i * 8 + p] = make_float4(acc0, acc1, acc2, acc3);
}

extern "C" void kernel_launch(void* const* d_in, const int* in_sizes, int n_in,
                              void* d_out, int out_size, void* d_ws, size_t ws_size,
                              hipStream_t stream) {
    const float* x  = (const float*)d_in[0];
    const float* W1 = (const float*)d_in[1];
    const float* b1 = (const float*)d_in[2];
    const float* W2 = (const float*)d_in[3];
    const float* b2 = (const float*)d_in[4];
    const int*   ei = (const int*)d_in[5];
    const int E = in_sizes[5] / 2;
    const int n = NNODES;
    const int* src = ei;
    const int* dst = ei + E;

    // workspace layout (floats):
    //   [0, n)        deg
    //   [n, 2n)       dis
    //   [2n, 18n)     h    (x@W1)
    //   [18n, 34n)    agg1 -> h1 (in place)
    //   [34n, 50n)    agg2
    float* ws   = (float*)d_ws;
    float* deg  = ws;
    float* dis  = ws + (size_t)n;
    float* h    = ws + (size_t)2 * n;
    float* agg1 = ws + (size_t)18 * n;
    float* agg2 = ws + (size_t)34 * n;

    // zero deg and both accumulators
    hipMemsetAsync(deg, 0, (size_t)n * sizeof(float), stream);
    hipMemsetAsync(agg1, 0, (size_t)32 * n * sizeof(float), stream);

    const int B = 256;
    k_deg<<<(E + B - 1) / B, B, 0, stream>>>(dst, E, deg);
    k_dis<<<(n + B - 1) / B, B, 0, stream>>>(deg, dis, n);
    k_xw1<<<(n + B - 1) / B, B, 0, stream>>>(x, W1, h, n);
    k_agg<<<(4 * E + B - 1) / B, B, 0, stream>>>(src, dst, dis, h, agg1, E);
    k_relu_bias_self<<<(4 * n + B - 1) / B, B, 0, stream>>>(agg1, h, dis, b1, agg1, n);
    k_agg<<<(4 * E + B - 1) / B, B, 0, stream>>>(src, dst, dis, agg1, agg2, E);
    k_out<<<(8 * n + B - 1) / B, B, 0, stream>>>(agg2, agg1, dis, W2, b2, (float*)d_out, n);
}

// Round 2
// 719.989 us; speedup vs baseline: 2.1725x; 2.1725x over previous
//
#include <hip/hip_runtime.h>

// QNetGNN: 2-layer GCN, N=100000, E=3.2M, F: 128 -> 16 -> 32.
// R2: CSR (counting sort by dst) built per-launch; gather-based aggregation
// (no feature atomics). Self-loop folded analytically; bias/relu fused into
// gather1; layer-2 matmul done post-aggregation on the 16-wide vector.

#define NNODES 100000
#define FIN    128
#define FHID   16
#define NACT   32

// ---- histogram of dst (in-degree, self loop excluded -> +1 later) ----
__global__ void k_count(const int* __restrict__ dst, int E, int* __restrict__ cnt) {
    int i = blockIdx.x * blockDim.x + threadIdx.x;
    if (i < E) atomicAdd(&cnt[dst[i]], 1);
}

// ---- dis = rsqrt(cnt + 1) ----
__global__ void k_dis(const int* __restrict__ cnt, float* __restrict__ dis, int n) {
    int i = blockIdx.x * blockDim.x + threadIdx.x;
    if (i < n) dis[i] = rsqrtf((float)cnt[i] + 1.0f);
}

// ---- exclusive scan of cnt -> rowptr[0..n], single block of 1024 ----
__global__ void k_scan(const int* __restrict__ cnt, int* __restrict__ rowptr, int n) {
    __shared__ int part[1024];
    int t = threadIdx.x;
    int chunk = (n + 1023) >> 10;
    int beg = t * chunk;
    int end = min(beg + chunk, n);
    int s = 0;
    for (int i = beg; i < end; ++i) s += cnt[i];
    part[t] = s;
    __syncthreads();
    for (int d = 1; d < 1024; d <<= 1) {
        int v = part[t];
        int add = (t >= d) ? part[t - d] : 0;
        __syncthreads();
        part[t] = v + add;
        __syncthreads();
    }
    int off = (t == 0) ? 0 : part[t - 1];
    for (int i = beg; i < end; ++i) { rowptr[i] = off; off += cnt[i]; }
    if (end == n) rowptr[n] = off;   // threads past the tail also write the total
}

// ---- bucket fill: csr[rowptr[d] + cursor[d]++] = src ----
__global__ void k_fill(const int* __restrict__ src, const int* __restrict__ dst,
                       const int* __restrict__ rowptr, int* __restrict__ cur,
                       int* __restrict__ csr, int E) {
    int i = blockIdx.x * blockDim.x + threadIdx.x;
    if (i >= E) return;
    int d = dst[i];
    int pos = atomicAdd(&cur[d], 1);
    csr[rowptr[d] + pos] = src[i];
}

// ---- h = x @ W1   [N,128]@[128,16] -> [N,16] ----
__global__ void k_xw1(const float* __restrict__ x, const float* __restrict__ W1,
                      float* __restrict__ h, int n) {
    __shared__ float w[FIN * FHID];   // 8 KB
    for (int i = threadIdx.x; i < FIN * FHID; i += blockDim.x) w[i] = W1[i];
    __syncthreads();
    int r = blockIdx.x * blockDim.x + threadIdx.x;
    if (r >= n) return;
    const float4* xr = (const float4*)(x + (long long)r * FIN);
    float acc[FHID];
#pragma unroll
    for (int c = 0; c < FHID; ++c) acc[c] = 0.f;
#pragma unroll 4
    for (int k4 = 0; k4 < FIN / 4; ++k4) {
        float4 xv = xr[k4];
        int k = k4 * 4;
#pragma unroll
        for (int c = 0; c < FHID; ++c) {
            acc[c] += xv.x * w[(k + 0) * FHID + c] + xv.y * w[(k + 1) * FHID + c]
                    + xv.z * w[(k + 2) * FHID + c] + xv.w * w[(k + 3) * FHID + c];
        }
    }
    float4* hr = (float4*)(h + (long long)r * FHID);
    hr[0] = make_float4(acc[0], acc[1], acc[2], acc[3]);
    hr[1] = make_float4(acc[4], acc[5], acc[6], acc[7]);
    hr[2] = make_float4(acc[8], acc[9], acc[10], acc[11]);
    hr[3] = make_float4(acc[12], acc[13], acc[14], acc[15]);
}

// ---- gather aggregation, 4 lanes per node, each owns one float4 chunk ----
// outv[i] = dis[i] * sum_e dis[src_e] * feat[src_e]  + feat_self[i]*dis[i]^2
//           (+ bias, relu if RELU)
template <bool RELU>
__global__ void k_gather(const int* __restrict__ rowptr, const int* __restrict__ csr,
                         const float* __restrict__ dis, const float* __restrict__ feat,
                         const float* __restrict__ bias, float* __restrict__ outv, int n) {
    int t = blockIdx.x * blockDim.x + threadIdx.x;
    int i = t >> 2, p = t & 3;
    if (i >= n) return;
    int beg = rowptr[i], end = rowptr[i + 1];
    float ax = 0.f, ay = 0.f, az = 0.f, aw = 0.f;
    for (int e = beg; e < end; ++e) {
        int s = csr[e];
        float w = dis[s];
        float4 v = ((const float4*)feat)[s * 4 + p];
        ax += v.x * w; ay += v.y * w; az += v.z * w; aw += v.w * w;
    }
    float di = dis[i];
    float sw = di * di;                       // self-loop norm 1/(deg+1)
    float4 hv = ((const float4*)feat)[i * 4 + p];
    float4 r;
    r.x = di * ax + hv.x * sw;
    r.y = di * ay + hv.y * sw;
    r.z = di * az + hv.z * sw;
    r.w = di * aw + hv.w * sw;
    if (RELU) {
        float4 bv = ((const float4*)bias)[p];
        r.x = fmaxf(r.x + bv.x, 0.f);
        r.y = fmaxf(r.y + bv.y, 0.f);
        r.z = fmaxf(r.z + bv.z, 0.f);
        r.w = fmaxf(r.w + bv.w, 0.f);
    }
    ((float4*)outv)[i * 4 + p] = r;
}

// ---- out = v @ W2 + b2   [N,16]@[16,32] -> [N,32], 8 lanes/node ----
__global__ void k_out(const float* __restrict__ v, const float* __restrict__ W2,
                      const float* __restrict__ b2, float* __restrict__ out, int n) {
    __shared__ float w[FHID * NACT];   // 2 KB
    __shared__ float bb[NACT];
    for (int i = threadIdx.x; i < FHID * NACT; i += blockDim.x) w[i] = W2[i];
    if (threadIdx.x < NACT) bb[threadIdx.x] = b2[threadIdx.x];
    __syncthreads();
    int t = blockIdx.x * blockDim.x + threadIdx.x;
    int i = t >> 3, p = t & 7;
    if (i >= n) return;
    float vv[FHID];
    const float4* v4 = (const float4*)(v + (long long)i * FHID);
#pragma unroll
    for (int q = 0; q < 4; ++q) {
        float4 a = v4[q];
        vv[q * 4 + 0] = a.x; vv[q * 4 + 1] = a.y; vv[q * 4 + 2] = a.z; vv[q * 4 + 3] = a.w;
    }
    float acc0 = bb[p * 4 + 0], acc1 = bb[p * 4 + 1], acc2 = bb[p * 4 + 2], acc3 = bb[p * 4 + 3];
#pragma unroll
    for (int c = 0; c < FHID; ++c) {
        float vc = vv[c];
        acc0 += vc * w[c * NACT + p * 4 + 0];
        acc1 += vc * w[c * NACT + p * 4 + 1];
        acc2 += vc * w[c * NACT + p * 4 + 2];
        acc3 += vc * w[c * NACT + p * 4 + 3];
    }
    ((float4*)out)[(long long)i * 8 + p] = make_float4(acc0, acc1, acc2, acc3);
}

extern "C" void kernel_launch(void* const* d_in, const int* in_sizes, int n_in,
                              void* d_out, int out_size, void* d_ws, size_t ws_size,
                              hipStream_t stream) {
    const float* x  = (const float*)d_in[0];
    const float* W1 = (const float*)d_in[1];
    const float* b1 = (const float*)d_in[2];
    const float* W2 = (const float*)d_in[3];
    const float* b2 = (const float*)d_in[4];
    const int*   ei = (const int*)d_in[5];
    const int E = in_sizes[5] / 2;
    const int n = NNODES;
    const int* src = ei;
    const int* dst = ei + E;

    // workspace layout:
    //   floats: dis [0,n)  h [n,17n)  h1 [17n,33n)  v2 [33n,49n)
    //   ints (after 49n floats): cnt [0,n) cur [n,2n) rowptr [2n,3n+1) csr [3n+1,3n+1+E)
    float* fb   = (float*)d_ws;
    float* dis  = fb;
    float* h    = fb + (size_t)n;
    float* h1   = fb + (size_t)17 * n;
    float* v2   = fb + (size_t)33 * n;
    int*   ib   = (int*)(fb + (size_t)49 * n);
    int*   cnt  = ib;
    int*   cur  = ib + (size_t)n;
    int*   rowptr = ib + (size_t)2 * n;
    int*   csr  = ib + (size_t)3 * n + 1;

    hipMemsetAsync(cnt, 0, (size_t)2 * n * sizeof(int), stream);  // cnt + cur

    const int B = 256;
    k_count<<<(E + B - 1) / B, B, 0, stream>>>(dst, E, cnt);
    k_dis<<<(n + B - 1) / B, B, 0, stream>>>(cnt, dis, n);
    k_scan<<<1, 1024, 0, stream>>>(cnt, rowptr, n);
    k_fill<<<(E + B - 1) / B, B, 0, stream>>>(src, dst, rowptr, cur, csr, E);
    k_xw1<<<(n + B - 1) / B, B, 0, stream>>>(x, W1, h, n);
    k_gather<true><<<(4 * n + B - 1) / B, B, 0, stream>>>(rowptr, csr, dis, h, b1, h1, n);
    k_gather<false><<<(4 * n + B - 1) / B, B, 0, stream>>>(rowptr, csr, dis, h1, nullptr, v2, n);
    k_out<<<(8 * n + B - 1) / B, B, 0, stream>>>(v2, W2, b2, (float*)d_out, n);
}